// Round 1
// baseline (185.776 us; speedup 1.0000x reference)
//
#include <hip/hip_runtime.h>
#include <hip/hip_bf16.h>
#include <math.h>

#define S_LEN 2048
#define EMB   1024
#define HEADS 16
#define HDIM  64

typedef __bf16 bf16x8 __attribute__((ext_vector_type(8)));
typedef float  f32x4  __attribute__((ext_vector_type(4)));

__device__ __forceinline__ bf16x8 cvt8(const float* v) {
    bf16x8 r;
#pragma unroll
    for (int i = 0; i < 8; ++i) r[i] = (__bf16)v[i];
    return r;
}

// ---------------- Attention kernel ----------------
// grid: N * H * (S/64) blocks; 256 threads (4 waves); wave w owns q-rows [w*16, w*16+16)
__global__ __launch_bounds__(256)
void attn_kernel(const float* __restrict__ Vp, const float* __restrict__ Kp,
                 const float* __restrict__ Qp, const int* __restrict__ Mp,
                 __bf16* __restrict__ Ob) {
    __shared__ __bf16 Klds[64][72];   // [kv][d]
    __shared__ __bf16 Vtlds[64][72];  // [d][kv]
    __shared__ __bf16 Plds[4][16][72];// per-wave [qrow][kv]

    const int tid  = threadIdx.x;
    const int lane = tid & 63;
    const int w    = tid >> 6;
    const int bid  = blockIdx.x;
    const int qt = bid & 31;
    const int h  = (bid >> 5) & 15;
    const int n  = bid >> 9;

    const float* qbase = Qp + (size_t)n * S_LEN * EMB + h * HDIM;
    const float* kbase = Kp + (size_t)n * S_LEN * EMB + h * HDIM;
    const float* vbase = Vp + (size_t)n * S_LEN * EMB + h * HDIM;
    const int*   mbase = Mp + (size_t)n * S_LEN * S_LEN;

    // Q fragments (A operand): row = lane&15 (+w*16), k = ks*32 + (lane>>4)*8 + e
    const int qrowA = qt * 64 + w * 16 + (lane & 15);
    bf16x8 qfrag[2];
    {
        const float* qp = qbase + (size_t)qrowA * EMB + ((lane >> 4) * 8);
        float tmp[8];
#pragma unroll
        for (int ks = 0; ks < 2; ++ks) {
            *(float4*)&tmp[0] = *(const float4*)(qp + ks * 32);
            *(float4*)&tmp[4] = *(const float4*)(qp + ks * 32 + 4);
            qfrag[ks] = cvt8(tmp);
        }
    }

    f32x4 oacc[4] = {};          // dt = 0..3 (d-subtiles of 16)
    float m_run[4], l_run[4];
#pragma unroll
    for (int r = 0; r < 4; ++r) { m_run[r] = -INFINITY; l_run[r] = 0.f; }

    const int srow = tid >> 2;         // staging row 0..63
    const int scol = (tid & 3) * 16;   // staging col group
    const int qrowD0 = qt * 64 + w * 16 + ((lane >> 4) * 4); // + reg

    for (int kv0 = 0; kv0 < S_LEN; kv0 += 64) {
        __syncthreads();
        // ---- stage K (row-major) and V^T (transposed) into LDS, f32->bf16
        {
            const float* ks = kbase + (size_t)(kv0 + srow) * EMB + scol;
            const float* vs = vbase + (size_t)(kv0 + srow) * EMB + scol;
            float tk[16], tv[16];
#pragma unroll
            for (int i = 0; i < 4; ++i) {
                *(float4*)&tk[i*4] = *(const float4*)(ks + i*4);
                *(float4*)&tv[i*4] = *(const float4*)(vs + i*4);
            }
            *(bf16x8*)&Klds[srow][scol]     = cvt8(&tk[0]);
            *(bf16x8*)&Klds[srow][scol + 8] = cvt8(&tk[8]);
#pragma unroll
            for (int i = 0; i < 16; ++i)
                Vtlds[scol + i][srow] = (__bf16)tv[i];
        }
        __syncthreads();

        // ---- QK^T: 4 key-subtiles of 16, K-dim = 64 in two MFMA k-steps
        f32x4 e[4];
#pragma unroll
        for (int jt = 0; jt < 4; ++jt) {
            bf16x8 k0 = *(const bf16x8*)&Klds[jt*16 + (lane & 15)][(lane >> 4) * 8];
            bf16x8 k1 = *(const bf16x8*)&Klds[jt*16 + (lane & 15)][32 + (lane >> 4) * 8];
            f32x4 z = {};
            z     = __builtin_amdgcn_mfma_f32_16x16x32_bf16(qfrag[0], k0, z, 0, 0, 0);
            e[jt] = __builtin_amdgcn_mfma_f32_16x16x32_bf16(qfrag[1], k1, z, 0, 0, 0);
        }

        // ---- mask + scale (mask==0 -> -1e20, then /sqrt(1024))
        float sc[4][4];
#pragma unroll
        for (int r = 0; r < 4; ++r) {
            const int* mrow = mbase + (size_t)(qrowD0 + r) * S_LEN + kv0 + (lane & 15);
#pragma unroll
            for (int jt = 0; jt < 4; ++jt) {
                int mv = mrow[jt * 16];
                sc[r][jt] = mv ? e[jt][r] * 0.03125f : -3.125e18f;
            }
        }

        // ---- online softmax (one m/l update per 64-key tile)
#pragma unroll
        for (int r = 0; r < 4; ++r) {
            float mx = fmaxf(fmaxf(sc[r][0], sc[r][1]), fmaxf(sc[r][2], sc[r][3]));
#pragma unroll
            for (int d = 1; d < 16; d <<= 1) mx = fmaxf(mx, __shfl_xor(mx, d));
            float mnew = fmaxf(m_run[r], mx);
            float corr = __expf(m_run[r] - mnew);
            m_run[r] = mnew;
            float psum = 0.f;
#pragma unroll
            for (int jt = 0; jt < 4; ++jt) {
                float p = __expf(sc[r][jt] - mnew);
                psum += p;
                Plds[w][(lane >> 4) * 4 + r][jt * 16 + (lane & 15)] = (__bf16)p;
            }
#pragma unroll
            for (int d = 1; d < 16; d <<= 1) psum += __shfl_xor(psum, d);
            l_run[r] = l_run[r] * corr + psum;
#pragma unroll
            for (int dt = 0; dt < 4; ++dt) oacc[dt][r] *= corr;
        }

        // ---- PV: P (A operand, via LDS transpose) x V^T-staged (B operand)
        bf16x8 pa0 = *(const bf16x8*)&Plds[w][lane & 15][(lane >> 4) * 8];
        bf16x8 pa1 = *(const bf16x8*)&Plds[w][lane & 15][32 + (lane >> 4) * 8];
#pragma unroll
        for (int dt = 0; dt < 4; ++dt) {
            bf16x8 v0 = *(const bf16x8*)&Vtlds[dt*16 + (lane & 15)][(lane >> 4) * 8];
            bf16x8 v1 = *(const bf16x8*)&Vtlds[dt*16 + (lane & 15)][32 + (lane >> 4) * 8];
            oacc[dt] = __builtin_amdgcn_mfma_f32_16x16x32_bf16(pa0, v0, oacc[dt], 0, 0, 0);
            oacc[dt] = __builtin_amdgcn_mfma_f32_16x16x32_bf16(pa1, v1, oacc[dt], 0, 0, 0);
        }
    }

    // ---- epilogue: normalize, store bf16 attention output to workspace
#pragma unroll
    for (int r = 0; r < 4; ++r) {
        float inv_l = 1.f / l_run[r];
        size_t row = (size_t)(qrowD0 + r);
        __bf16* op = Ob + (size_t)n * S_LEN * EMB + row * EMB + h * HDIM + (lane & 15);
#pragma unroll
        for (int dt = 0; dt < 4; ++dt)
            op[dt * 16] = (__bf16)(oacc[dt][r] * inv_l);
    }
}

// ---------------- FC kernel: Out = X @ W^T + b ----------------
// X: [4096][1024] bf16 (workspace), W: [1024][1024] f32 row-major (K-contig), Out f32
__global__ __launch_bounds__(256)
void fc_kernel(const __bf16* __restrict__ X, const float* __restrict__ Wf,
               const float* __restrict__ bfc, float* __restrict__ Out) {
    __shared__ __bf16 Alds[64][40];
    __shared__ __bf16 Blds[64][40];
    const int tid  = threadIdx.x;
    const int lane = tid & 63;
    const int w    = tid >> 6;
    const int bm = blockIdx.x >> 4;
    const int bn = blockIdx.x & 15;

    const int srow = tid >> 2;
    const int scol = (tid & 3) * 8;

    f32x4 acc[4] = {};

    for (int k0 = 0; k0 < EMB; k0 += 32) {
        __syncthreads();
        *(bf16x8*)&Alds[srow][scol] =
            *(const bf16x8*)(X + (size_t)(bm*64 + srow) * EMB + k0 + scol);
        {
            float tb[8];
            const float* wp = Wf + (size_t)(bn*64 + srow) * EMB + k0 + scol;
            *(float4*)&tb[0] = *(const float4*)wp;
            *(float4*)&tb[4] = *(const float4*)(wp + 4);
            *(bf16x8*)&Blds[srow][scol] = cvt8(tb);
        }
        __syncthreads();
        bf16x8 a = *(const bf16x8*)&Alds[w*16 + (lane & 15)][(lane >> 4) * 8];
#pragma unroll
        for (int jt = 0; jt < 4; ++jt) {
            bf16x8 b = *(const bf16x8*)&Blds[jt*16 + (lane & 15)][(lane >> 4) * 8];
            acc[jt] = __builtin_amdgcn_mfma_f32_16x16x32_bf16(a, b, acc[jt], 0, 0, 0);
        }
    }

    const int row0 = bm*64 + w*16 + (lane >> 4) * 4;
#pragma unroll
    for (int jt = 0; jt < 4; ++jt) {
        int col = bn*64 + jt*16 + (lane & 15);
        float bias = bfc[col];
#pragma unroll
        for (int r = 0; r < 4; ++r)
            Out[(size_t)(row0 + r) * EMB + col] = acc[jt][r] + bias;
    }
}

extern "C" void kernel_launch(void* const* d_in, const int* in_sizes, int n_in,
                              void* d_out, int out_size, void* d_ws, size_t ws_size,
                              hipStream_t stream) {
    const float* Vp = (const float*)d_in[0];   // value
    const float* Kp = (const float*)d_in[1];   // key
    const float* Qp = (const float*)d_in[2];   // query
    const int*   Mp = (const int*)d_in[3];     // mask
    const float* Wf = (const float*)d_in[4];   // W_fc
    const float* bf = (const float*)d_in[5];   // b_fc
    float* Out = (float*)d_out;
    __bf16* attn = (__bf16*)d_ws;              // 2*2048*1024 bf16 = 8 MB

    attn_kernel<<<dim3(2 * HEADS * (S_LEN / 64)), dim3(256), 0, stream>>>(Vp, Kp, Qp, Mp, attn);
    fc_kernel<<<dim3((4096 / 64) * (EMB / 64)), dim3(256), 0, stream>>>(attn, Wf, bf, Out);
}

// Round 3
// 185.741 us; speedup vs baseline: 1.0002x; 1.0002x over previous
//
#include <hip/hip_runtime.h>
#include <hip/hip_bf16.h>
#include <math.h>

#define S_LEN 2048
#define EMB   1024
#define HEADS 16
#define HDIM  64

// softmax computed in exp2 domain: p = exp2(e * log2e/32); masked -> -3.125e18*log2e
#define C_SCALE  0.045084439f
#define MASK_NEG -4.5084439e18f

typedef __bf16 bf16x8 __attribute__((ext_vector_type(8)));
typedef float  f32x4  __attribute__((ext_vector_type(4)));

__device__ __forceinline__ bf16x8 cvt8(const float* v) {
    bf16x8 r;
#pragma unroll
    for (int i = 0; i < 8; ++i) r[i] = (__bf16)v[i];
    return r;
}

// ---------------- Attention kernel (swapped-operand flash) ----------------
// grid: 512 blocks = N(2) x H(16) x (S/128); 256 threads (4 waves); wave owns 32 q rows.
__global__ __launch_bounds__(256)
void attn_kernel(const float* __restrict__ Vp, const float* __restrict__ Kp,
                 const float* __restrict__ Qp, const int* __restrict__ Mp,
                 __bf16* __restrict__ Ob) {
    __shared__ __bf16 Klds[64 * 64];        // [kv][d] row-major, XOR-swizzled, 8KB
    __shared__ __bf16 Vtlds[64 * 64];       // [d][kv] transposed, XOR-swizzled, 8KB
    __shared__ __bf16 Plds[4][32][72];      // per-wave [q][kv], stride 72, 18KB

    const int tid  = threadIdx.x;
    const int lane = tid & 63;
    const int w    = tid >> 6;
    // XCD-aware swizzle (512 % 8 == 0 -> bijective)
    const int bid = (blockIdx.x & 7) * 64 + (blockIdx.x >> 3);
    const int qt = bid & 15;
    const int h  = (bid >> 4) & 15;
    const int n  = bid >> 8;

    const int ql = lane & 15;
    const int g  = lane >> 4;

    const float* qbase = Qp + (size_t)n * S_LEN * EMB + h * HDIM;
    const float* kbase = Kp + (size_t)n * S_LEN * EMB + h * HDIM;
    const float* vbase = Vp + (size_t)n * S_LEN * EMB + h * HDIM;
    const int*   mbase = Mp + (size_t)n * S_LEN * S_LEN;

    const int qw = qt * 128 + w * 32;   // wave's first q row

    // Q fragments (B operand): lane holds Q[qw+qf*16+ql][ks*32 + g*8 + e]
    bf16x8 qfrag[2][2];
#pragma unroll
    for (int qf = 0; qf < 2; ++qf) {
        const float* qp = qbase + (size_t)(qw + qf * 16 + ql) * EMB + g * 8;
#pragma unroll
        for (int ks = 0; ks < 2; ++ks) {
            float tmp[8];
            *(float4*)&tmp[0] = *(const float4*)(qp + ks * 32);
            *(float4*)&tmp[4] = *(const float4*)(qp + ks * 32 + 4);
            qfrag[qf][ks] = cvt8(tmp);
        }
    }

    f32x4 oacc[2][4] = {};              // [qf][dt]: lane's q = qw+qf*16+ql, d = dt*16+g*4+r
    float m_run[2] = {-INFINITY, -INFINITY};
    float l_run[2] = {0.f, 0.f};

    const int sd0 = (tid & 31) * 2;     // staging: d column pair
    const int sk0 = (tid >> 5) * 8;     // staging: kv row block of 8

    for (int kv0 = 0; kv0 < S_LEN; kv0 += 64) {
        __syncthreads();
        // ---- stage K row-major + V transposed, both XOR-swizzled ----
        {
            const float* kp = kbase + (size_t)(kv0 + sk0) * EMB + sd0;
            const float* vp = vbase + (size_t)(kv0 + sk0) * EMB + sd0;
            float2 kk[8], vv[8];
#pragma unroll
            for (int j = 0; j < 8; ++j) {
                kk[j] = *(const float2*)(kp + (size_t)j * EMB);
                vv[j] = *(const float2*)(vp + (size_t)j * EMB);
            }
#pragma unroll
            for (int j = 0; j < 8; ++j) {
                int row = sk0 + j;
                __bf16 two[2] = {(__bf16)kk[j].x, (__bf16)kk[j].y};
                *(unsigned*)((char*)Klds + row * 128 + ((sd0 * 2) ^ ((row & 7) << 4))) =
                    *(unsigned*)two;
            }
            __bf16 r0[8], r1[8];
#pragma unroll
            for (int j = 0; j < 8; ++j) { r0[j] = (__bf16)vv[j].x; r1[j] = (__bf16)vv[j].y; }
            *(bf16x8*)((char*)Vtlds + sd0 * 128       + ((sk0 * 2) ^ ((sd0 & 7) << 4)))       = *(bf16x8*)r0;
            *(bf16x8*)((char*)Vtlds + (sd0 + 1) * 128 + ((sk0 * 2) ^ (((sd0 + 1) & 7) << 4))) = *(bf16x8*)r1;
        }
        __syncthreads();

        // ---- QK^T swapped: e[jt][qf] = P^T tile, rows k, cols q ----
        f32x4 e[4][2];
#pragma unroll
        for (int jt = 0; jt < 4; ++jt) {
            int row = jt * 16 + ql;
            bf16x8 k0 = *(const bf16x8*)((char*)Klds + row * 128 + ((g * 16)      ^ ((row & 7) << 4)));
            bf16x8 k1 = *(const bf16x8*)((char*)Klds + row * 128 + ((64 + g * 16) ^ ((row & 7) << 4)));
#pragma unroll
            for (int qf = 0; qf < 2; ++qf) {
                f32x4 z = {};
                z          = __builtin_amdgcn_mfma_f32_16x16x32_bf16(k0, qfrag[qf][0], z, 0, 0, 0);
                e[jt][qf]  = __builtin_amdgcn_mfma_f32_16x16x32_bf16(k1, qfrag[qf][1], z, 0, 0, 0);
            }
        }

        // ---- mask + online softmax (lane-local q) ----
#pragma unroll
        for (int qf = 0; qf < 2; ++qf) {
            const int* mrow = mbase + (size_t)(qw + qf * 16 + ql) * S_LEN + kv0 + g * 4;
            float sc[4][4];
#pragma unroll
            for (int jt = 0; jt < 4; ++jt) {
                int4 mv = *(const int4*)(mrow + jt * 16);
                sc[jt][0] = mv.x ? e[jt][qf][0] * C_SCALE : MASK_NEG;
                sc[jt][1] = mv.y ? e[jt][qf][1] * C_SCALE : MASK_NEG;
                sc[jt][2] = mv.z ? e[jt][qf][2] * C_SCALE : MASK_NEG;
                sc[jt][3] = mv.w ? e[jt][qf][3] * C_SCALE : MASK_NEG;
            }
            float mx = sc[0][0];
#pragma unroll
            for (int jt = 0; jt < 4; ++jt)
#pragma unroll
                for (int r = 0; r < 4; ++r) mx = fmaxf(mx, sc[jt][r]);
            mx = fmaxf(mx, __shfl_xor(mx, 16));
            mx = fmaxf(mx, __shfl_xor(mx, 32));
            float mnew = fmaxf(m_run[qf], mx);
            float corr = exp2f(m_run[qf] - mnew);
            m_run[qf] = mnew;

            float p[16];
            float psum = 0.f;
#pragma unroll
            for (int jt = 0; jt < 4; ++jt)
#pragma unroll
                for (int r = 0; r < 4; ++r) {
                    float v = exp2f(sc[jt][r] - mnew);
                    p[jt * 4 + r] = v;
                    psum += v;
                }
            psum += __shfl_xor(psum, 16);
            psum += __shfl_xor(psum, 32);
            l_run[qf] = l_run[qf] * corr + psum;
#pragma unroll
            for (int dt = 0; dt < 4; ++dt) oacc[qf][dt] *= corr;

#pragma unroll
            for (int jt = 0; jt < 4; ++jt) {
                __bf16 pb[4] = {(__bf16)p[jt * 4], (__bf16)p[jt * 4 + 1],
                                (__bf16)p[jt * 4 + 2], (__bf16)p[jt * 4 + 3]};
                *(unsigned long long*)&Plds[w][qf * 16 + ql][jt * 16 + g * 4] =
                    *(unsigned long long*)pb;
            }
        }

        // ---- PV swapped: oacc[d][q] += Vt x P ----
        bf16x8 pf[2][2];  // [ks][qf]
#pragma unroll
        for (int qf = 0; qf < 2; ++qf)
#pragma unroll
            for (int ks = 0; ks < 2; ++ks)
                pf[ks][qf] = *(const bf16x8*)&Plds[w][qf * 16 + ql][ks * 32 + g * 8];
#pragma unroll
        for (int dt = 0; dt < 4; ++dt) {
            int row = dt * 16 + ql;
            bf16x8 v0 = *(const bf16x8*)((char*)Vtlds + row * 128 + ((g * 16)      ^ ((row & 7) << 4)));
            bf16x8 v1 = *(const bf16x8*)((char*)Vtlds + row * 128 + ((64 + g * 16) ^ ((row & 7) << 4)));
#pragma unroll
            for (int qf = 0; qf < 2; ++qf) {
                oacc[qf][dt] = __builtin_amdgcn_mfma_f32_16x16x32_bf16(v0, pf[0][qf], oacc[qf][dt], 0, 0, 0);
                oacc[qf][dt] = __builtin_amdgcn_mfma_f32_16x16x32_bf16(v1, pf[1][qf], oacc[qf][dt], 0, 0, 0);
            }
        }
    }

    // ---- epilogue: normalize + bf16 store to workspace ----
#pragma unroll
    for (int qf = 0; qf < 2; ++qf) {
        float inv = 1.f / l_run[qf];
        __bf16* op = Ob + (size_t)n * S_LEN * EMB + (size_t)(qw + qf * 16 + ql) * EMB + h * HDIM;
#pragma unroll
        for (int dt = 0; dt < 4; ++dt) {
            __bf16 ob[4] = {(__bf16)(oacc[qf][dt][0] * inv), (__bf16)(oacc[qf][dt][1] * inv),
                            (__bf16)(oacc[qf][dt][2] * inv), (__bf16)(oacc[qf][dt][3] * inv)};
            *(unsigned long long*)(op + dt * 16 + g * 4) = *(unsigned long long*)ob;
        }
    }
}

// ---------------- FC kernel: Out = X @ W^T + b ----------------
__global__ __launch_bounds__(256)
void fc_kernel(const __bf16* __restrict__ X, const float* __restrict__ Wf,
               const float* __restrict__ bfc, float* __restrict__ Out) {
    __shared__ __bf16 Alds[64][40];
    __shared__ __bf16 Blds[64][40];
    const int tid  = threadIdx.x;
    const int lane = tid & 63;
    const int w    = tid >> 6;
    const int bm = blockIdx.x >> 4;
    const int bn = blockIdx.x & 15;

    const int srow = tid >> 2;
    const int scol = (tid & 3) * 8;

    f32x4 acc[4] = {};

    for (int k0 = 0; k0 < EMB; k0 += 32) {
        __syncthreads();
        *(bf16x8*)&Alds[srow][scol] =
            *(const bf16x8*)(X + (size_t)(bm * 64 + srow) * EMB + k0 + scol);
        {
            float tb[8];
            const float* wp = Wf + (size_t)(bn * 64 + srow) * EMB + k0 + scol;
            *(float4*)&tb[0] = *(const float4*)wp;
            *(float4*)&tb[4] = *(const float4*)(wp + 4);
            *(bf16x8*)&Blds[srow][scol] = cvt8(tb);
        }
        __syncthreads();
        bf16x8 a = *(const bf16x8*)&Alds[w * 16 + (lane & 15)][(lane >> 4) * 8];
#pragma unroll
        for (int jt = 0; jt < 4; ++jt) {
            bf16x8 b = *(const bf16x8*)&Blds[jt * 16 + (lane & 15)][(lane >> 4) * 8];
            acc[jt] = __builtin_amdgcn_mfma_f32_16x16x32_bf16(a, b, acc[jt], 0, 0, 0);
        }
    }

    const int row0 = bm * 64 + w * 16 + (lane >> 4) * 4;
#pragma unroll
    for (int jt = 0; jt < 4; ++jt) {
        int col = bn * 64 + jt * 16 + (lane & 15);
        float bias = bfc[col];
#pragma unroll
        for (int r = 0; r < 4; ++r)
            Out[(size_t)(row0 + r) * EMB + col] = acc[jt][r] + bias;
    }
}

extern "C" void kernel_launch(void* const* d_in, const int* in_sizes, int n_in,
                              void* d_out, int out_size, void* d_ws, size_t ws_size,
                              hipStream_t stream) {
    const float* Vp = (const float*)d_in[0];
    const float* Kp = (const float*)d_in[1];
    const float* Qp = (const float*)d_in[2];
    const int*   Mp = (const int*)d_in[3];
    const float* Wf = (const float*)d_in[4];
    const float* bf = (const float*)d_in[5];
    float* Out = (float*)d_out;
    __bf16* attn = (__bf16*)d_ws;   // 2*2048*1024 bf16 = 8 MB

    attn_kernel<<<dim3(2 * HEADS * (S_LEN / 128)), dim3(256), 0, stream>>>(Vp, Kp, Qp, Mp, attn);
    fc_kernel<<<dim3((2 * S_LEN / 64) * (EMB / 64)), dim3(256), 0, stream>>>(attn, Wf, bf, Out);
}